// Round 14
// baseline (275.250 us; speedup 1.0000x reference)
//
#include <hip/hip_runtime.h>
#include <hip/hip_bf16.h>

typedef __hip_bfloat16 obf;
typedef __attribute__((ext_vector_type(8))) __bf16 bf16x8;
typedef __attribute__((ext_vector_type(4))) float f32x4;

#define DEVINL __device__ __forceinline__

DEVINL void gload_lds16(const void* g, void* l) {
  __builtin_amdgcn_global_load_lds((const __attribute__((address_space(1))) void*)g,
                                   (__attribute__((address_space(3))) void*)l,
                                   16, 0, 0);
}

// ---------------- f32 -> bf16 conversion (weights) ----------------
__global__ void __launch_bounds__(256) f2b_kernel(const float* __restrict__ in,
                                                  __bf16* __restrict__ out, int n8)
{
  const int i = blockIdx.x * 256 + threadIdx.x;
  if (i >= n8) return;
  const float4 a = ((const float4*)in)[i * 2];
  const float4 b = ((const float4*)in)[i * 2 + 1];
  bf16x8 o;
  o[0] = (__bf16)a.x; o[1] = (__bf16)a.y; o[2] = (__bf16)a.z; o[3] = (__bf16)a.w;
  o[4] = (__bf16)b.x; o[5] = (__bf16)b.y; o[6] = (__bf16)b.z; o[7] = (__bf16)b.w;
  ((bf16x8*)out)[i] = o;
}

// ---------------- LayerNorm (one row per block, C=1024), f32 in -> bf16 out ----------------
__global__ void __launch_bounds__(256) ln_kernel(const float* __restrict__ xin,
    const float* __restrict__ g, const float* __restrict__ b, obf* __restrict__ out)
{
  const int row = blockIdx.x;
  const int t = threadIdx.x;
  const int lane = t & 63, w = t >> 6;
  float4 f = ((const float4*)xin)[(size_t)row * 256 + t];
  float v[4] = { f.x, f.y, f.z, f.w };
  float s1 = v[0] + v[1] + v[2] + v[3];
  float s2 = v[0]*v[0] + v[1]*v[1] + v[2]*v[2] + v[3]*v[3];
  #pragma unroll
  for (int off = 32; off >= 1; off >>= 1) {
    s1 += __shfl_xor(s1, off);
    s2 += __shfl_xor(s2, off);
  }
  __shared__ float red[8];
  if (lane == 0) { red[w] = s1; red[4 + w] = s2; }
  __syncthreads();
  s1 = red[0] + red[1] + red[2] + red[3];
  s2 = red[4] + red[5] + red[6] + red[7];
  const float mu = s1 * (1.f / 1024.f);
  const float var = s2 * (1.f / 1024.f) - mu * mu;
  const float rs = rsqrtf(var + 1e-5f);
  const float4 gv = ((const float4*)g)[t];
  const float4 bv = ((const float4*)b)[t];
  obf* op = out + (size_t)row * 1024 + t * 4;
  op[0] = __float2bfloat16((v[0] - mu) * rs * gv.x + bv.x);
  op[1] = __float2bfloat16((v[1] - mu) * rs * gv.y + bv.y);
  op[2] = __float2bfloat16((v[2] - mu) * rs * gv.z + bv.z);
  op[3] = __float2bfloat16((v[3] - mu) * rs * gv.w + bv.w);
}

// ---------------- GEMM: C[M,N] = A[M,K] @ W[N,K]^T (+ epilogue) ----------------
// ROUND-14: 2-deep pipelined double-buffer, ONE __syncthreads per K-step.
// Ordering [sync -> stage(next, buf^1) -> ds_read/MFMA(buf)] is race-free:
// the sync's implicit vmcnt(0)+lgkmcnt(0)+all-wave barrier guarantees both
// (a) this tile's loads (issued a full phase ago) landed, and (b) the buffer
// being overwritten was consumed last phase. Loads drained at each barrier
// have had the whole compute phase in flight -> drain cost ~0 (T3-minimum,
// m230/m248: 655-682 TF). LDS: NI=4 64KB (2 blk/CU), NI=2 48KB (3 blk/CU).
enum { EPI_NONE = 0, EPI_BIAS_RES_F32OUT = 1, EPI_BIAS_GELU = 2, EPI_BIAS_RESF32_F32OUT = 3 };

template<int EPI, int NI>
__global__ void __launch_bounds__(256, 2) gemm_bt(
    const obf* __restrict__ A, const obf* __restrict__ Bw,
    void* __restrict__ Cout, const float* __restrict__ bias,
    const void* __restrict__ resid, int M, int N, int K)
{
  constexpr int ABUF = 128 * 64 * 2;
  constexpr int BBUF = NI * 32 * 64 * 2;
  __shared__ __align__(16) char As[2 * ABUF];
  __shared__ __align__(16) char Bs[2 * BBUF];
  const int tid = threadIdx.x;
  const int lane = tid & 63;
  const int w = tid >> 6, wr = w >> 1, wc = w & 1;
  const int bm = blockIdx.y * 128, bn = blockIdx.x * (NI * 32);
  const size_t lda = (size_t)K * 2;

  auto stage = [&](int buf, int k0) {
    #pragma unroll
    for (int i = 0; i < 4; i++) {
      const int ci = tid + 256 * i;
      const int r = ci >> 3;
      const int gb = ((ci & 7) * 16) ^ ((r & 7) << 4);
      gload_lds16((const char*)A + (size_t)(bm + r) * lda + (size_t)k0 * 2 + gb,
                  As + buf * ABUF + ci * 16);
    }
    #pragma unroll
    for (int i = 0; i < NI; i++) {
      const int ci = tid + 256 * i;
      const int r = ci >> 3;
      const int gb = ((ci & 7) * 16) ^ ((r & 7) << 4);
      gload_lds16((const char*)Bw + (size_t)(bn + r) * lda + (size_t)k0 * 2 + gb,
                  Bs + buf * BBUF + ci * 16);
    }
  };

  f32x4 acc[4][NI];
  #pragma unroll
  for (int i = 0; i < 4; i++)
    #pragma unroll
    for (int j = 0; j < NI; j++) {
      acc[i][j][0] = 0.f; acc[i][j][1] = 0.f; acc[i][j][2] = 0.f; acc[i][j][3] = 0.f;
    }

  stage(0, 0);
  int cur = 0;
  for (int k0 = 0; k0 < K; k0 += 64) {
    __syncthreads();                       // tile-t landed everywhere; buf^1 reads drained
    if (k0 + 64 < K) stage(cur ^ 1, k0 + 64);   // next tile flies under this compute
    const char* Ab = As + cur * ABUF;
    const char* Bb = Bs + cur * BBUF;

    bf16x8 af[4][2], bfr[NI][2];
    #pragma unroll
    for (int mi = 0; mi < 4; mi++) {
      const int r = wr * 64 + mi * 16 + (lane & 15);
      #pragma unroll
      for (int ks = 0; ks < 2; ks++) {
        const int cb = ks * 64 + ((lane >> 4) * 16);
        af[mi][ks] = *(const bf16x8*)(Ab + r * 128 + (cb ^ ((r & 7) << 4)));
      }
    }
    #pragma unroll
    for (int ni = 0; ni < NI; ni++) {
      const int r = wc * (NI * 16) + ni * 16 + (lane & 15);
      #pragma unroll
      for (int ks = 0; ks < 2; ks++) {
        const int cb = ks * 64 + ((lane >> 4) * 16);
        bfr[ni][ks] = *(const bf16x8*)(Bb + r * 128 + (cb ^ ((r & 7) << 4)));
      }
    }
    #pragma unroll
    for (int ks = 0; ks < 2; ks++)
      #pragma unroll
      for (int mi = 0; mi < 4; mi++)
        #pragma unroll
        for (int ni = 0; ni < NI; ni++)
          acc[mi][ni] = __builtin_amdgcn_mfma_f32_16x16x32_bf16(af[mi][ks], bfr[ni][ks], acc[mi][ni], 0, 0, 0);
    cur ^= 1;
  }

  #pragma unroll
  for (int mi = 0; mi < 4; mi++) {
    #pragma unroll
    for (int ni = 0; ni < NI; ni++) {
      const int col = bn + wc * (NI * 16) + ni * 16 + (lane & 15);
      float bv = 0.f;
      if (EPI != EPI_NONE) bv = bias[col];
      #pragma unroll
      for (int r = 0; r < 4; r++) {
        const int row = bm + wr * 64 + mi * 16 + ((lane >> 4) << 2) + r;
        const float vacc = acc[mi][ni][r];
        const size_t idx = (size_t)row * N + col;
        if (EPI == EPI_NONE) {
          ((obf*)Cout)[idx] = __float2bfloat16(vacc);
        } else if (EPI == EPI_BIAS_RES_F32OUT) {
          const float x0 = ((const float*)resid)[idx];
          ((float*)Cout)[idx] = vacc + bv + x0;
        } else if (EPI == EPI_BIAS_GELU) {
          const float u = vacc + bv;
          ((obf*)Cout)[idx] = __float2bfloat16(0.5f * u * (1.f + erff(u * 0.70710678118f)));
        } else {   // EPI_BIAS_RESF32_F32OUT
          const float x0 = ((const float*)resid)[idx];
          ((float*)Cout)[idx] = vacc + bv + x0;
        }
      }
    }
  }
}

// ---------------- V transpose: vt[b][h][d][n] = qkv[b][n][2C + h*64 + d] ----------------
__global__ void __launch_bounds__(256) vtrans_kernel(const obf* __restrict__ qkv, obf* __restrict__ vt)
{
  const int bh = blockIdx.y;             // 0..31  (b*16+h)
  const int b = bh >> 4, h = bh & 15;
  const int n0 = blockIdx.x * 64;        // 32 tiles over N=2048
  __shared__ __bf16 tile[64][72];        // +8 pad
  const int t = threadIdx.x;
  {
    const int n = t >> 2;
    const int c0 = (t & 3) * 16;
    const __bf16* src = (const __bf16*)qkv + ((size_t)(b * 2048 + n0 + n)) * 3072 + 2048 + h * 64 + c0;
    bf16x8 u0 = *(const bf16x8*)src;
    bf16x8 u1 = *(const bf16x8*)(src + 8);
    #pragma unroll
    for (int j = 0; j < 8; j++) { tile[n][c0 + j] = u0[j]; tile[n][c0 + 8 + j] = u1[j]; }
  }
  __syncthreads();
  {
    const int d = t >> 2;
    const int c0 = (t & 3) * 16;
    bf16x8 o0, o1;
    #pragma unroll
    for (int j = 0; j < 8; j++) { o0[j] = tile[c0 + j][d]; o1[j] = tile[c0 + 8 + j][d]; }
    __bf16* dst = (__bf16*)vt + ((size_t)bh * 64 + d) * 2048 + n0 + c0;
    *(bf16x8*)dst = o0;
    *(bf16x8*)(dst + 8) = o1;
  }
}

// ---------------- Flash attention fwd ----------------
// ROUND-13 structure kept: 512 threads / 8 waves, Q-tile 128 (wave = 16 q rows),
// KV=64 reg-staged T14 pipeline, no-max softmax, XCD swizzle. LDS 32KB.
__global__ void __launch_bounds__(512, 2) attn_kernel(
    const obf* __restrict__ qkv_, const obf* __restrict__ vt_, obf* __restrict__ ao)
{
  const __bf16* qkv = (const __bf16*)qkv_;
  const __bf16* vt  = (const __bf16*)vt_;
  const int bid = blockIdx.x;            // 0..511
  const int xcd = bid & 7, idx = bid >> 3;
  const int bh = xcd * 4 + (idx >> 4);   // 4 bh per XCD (K/V L2-resident)
  const int q0 = (idx & 15) * 128;
  const int b = bh >> 4, h = bh & 15;
  const int tid = threadIdx.x, lane = tid & 63, w = tid >> 6;   // w 0..7
  const int l15 = lane & 15, hi = lane >> 4;

  __shared__ __align__(16) char Ks[64 * 128];      // [kv=64][d=64]*2B, swizzled
  __shared__ __align__(16) char Vs[64 * 128];      // [d=64][kv=64]*2B, swizzled
  __shared__ __align__(16) char Ps[8 * 16 * 128];  // per-wave [16 q][64 kv]*2B, swz

  bf16x8 qf[2];
  {
    const int qrow = q0 + w * 16 + l15;
    #pragma unroll
    for (int ks = 0; ks < 2; ks++)
      qf[ks] = *(const bf16x8*)(qkv + ((size_t)(b * 2048 + qrow)) * 3072 + h * 64 + ks * 32 + hi * 8);
  }

  f32x4 o[4];
  #pragma unroll
  for (int j = 0; j < 4; j++) { o[j][0]=0.f; o[j][1]=0.f; o[j][2]=0.f; o[j][3]=0.f; }
  float lrow[4] = { 0.f, 0.f, 0.f, 0.f };

  const float kfac = 0.125f * 1.44269504089f;  // scale * log2(e)

  bf16x8 pk, pv;
  {
    const int kr = tid >> 3, kc = (tid & 7) * 8;
    pk = *(const bf16x8*)(qkv + ((size_t)(b * 2048 + kr)) * 3072 + 1024 + h * 64 + kc);
    pv = *(const bf16x8*)(vt + ((size_t)bh * 64 + kr) * 2048 + kc);
  }
  {
    const int kr = tid >> 3, kcb = (tid & 7) * 16;
    *(bf16x8*)(Ks + kr * 128 + (kcb ^ ((kr & 7) << 4))) = pk;
    *(bf16x8*)(Vs + kr * 128 + (kcb ^ ((kr & 7) << 4))) = pv;
  }
  __syncthreads();

  for (int kt = 0; kt < 2048; kt += 64) {
    if (kt + 64 < 2048) {
      const int kr = tid >> 3, kc = (tid & 7) * 8;
      pk = *(const bf16x8*)(qkv + ((size_t)(b * 2048 + kt + 64 + kr)) * 3072 + 1024 + h * 64 + kc);
      pv = *(const bf16x8*)(vt + ((size_t)bh * 64 + kr) * 2048 + kt + 64 + kc);
    }

    f32x4 s[4];
    #pragma unroll
    for (int j = 0; j < 4; j++) { s[j][0]=0.f; s[j][1]=0.f; s[j][2]=0.f; s[j][3]=0.f; }
    #pragma unroll
    for (int ni = 0; ni < 4; ni++) {
      const int r = ni * 16 + l15;
      const bf16x8 kf0 = *(const bf16x8*)(Ks + r * 128 + ((hi * 16) ^ ((r & 7) << 4)));
      const bf16x8 kf1 = *(const bf16x8*)(Ks + r * 128 + ((64 + hi * 16) ^ ((r & 7) << 4)));
      s[ni] = __builtin_amdgcn_mfma_f32_16x16x32_bf16(qf[0], kf0, s[ni], 0, 0, 0);
      s[ni] = __builtin_amdgcn_mfma_f32_16x16x32_bf16(qf[1], kf1, s[ni], 0, 0, 0);
    }

    #pragma unroll
    for (int r = 0; r < 4; r++) {
      const int qrl = (hi << 2) + r;
      char* psrow = Ps + w * 2048 + qrl * 128;
      float psum = 0.f;
      #pragma unroll
      for (int ni = 0; ni < 4; ni++) {
        const float p = exp2f(s[ni][r] * kfac);
        psum += p;
        *(__bf16*)(psrow + (((ni * 16 + l15) * 2) ^ ((qrl & 7) << 4))) = (__bf16)p;
      }
      lrow[r] += psum;
    }

    #pragma unroll
    for (int ks = 0; ks < 2; ks++) {
      const int rr = l15;
      const bf16x8 pa = *(const bf16x8*)(Ps + w * 2048 + rr * 128 + (((ks * 32 + hi * 8) * 2) ^ ((rr & 7) << 4)));
      #pragma unroll
      for (int df = 0; df < 4; df++) {
        const int dr = df * 16 + l15;
        const int cb = (ks * 32 + hi * 8) * 2;
        const bf16x8 vb = *(const bf16x8*)(Vs + dr * 128 + (cb ^ ((dr & 7) << 4)));
        o[df] = __builtin_amdgcn_mfma_f32_16x16x32_bf16(pa, vb, o[df], 0, 0, 0);
      }
    }

    __syncthreads();
    if (kt + 64 < 2048) {
      const int kr = tid >> 3, kcb = (tid & 7) * 16;
      *(bf16x8*)(Ks + kr * 128 + (kcb ^ ((kr & 7) << 4))) = pk;
      *(bf16x8*)(Vs + kr * 128 + (kcb ^ ((kr & 7) << 4))) = pv;
    }
    __syncthreads();
  }

  #pragma unroll
  for (int r = 0; r < 4; r++) {
    lrow[r] += __shfl_xor(lrow[r], 1);
    lrow[r] += __shfl_xor(lrow[r], 2);
    lrow[r] += __shfl_xor(lrow[r], 4);
    lrow[r] += __shfl_xor(lrow[r], 8);
  }
  #pragma unroll
  for (int r = 0; r < 4; r++) {
    const float inv = 1.f / lrow[r];
    const int qrow = q0 + w * 16 + (hi << 2) + r;
    #pragma unroll
    for (int df = 0; df < 4; df++) {
      const int col = h * 64 + df * 16 + l15;
      ao[((size_t)(b * 2048 + qrow)) * 1024 + col] = __float2bfloat16(o[df][r] * inv);
    }
  }
}

// ---------------- launch ----------------
// ws layout (64 MB total, slots time-multiplexed):
//   [ 0,16M)  x2   f32 [4096][1024]
//   [16,24M)  h    bf16 [4096][1024]          -> later wb_w2 (8MB) after h dies
//   [24,48M)  qkv  bf16 [4096][3072]          -> later part of m1
//   [48,56M)  ao   bf16 [4096][1024]          -> later part of m1 (m1 spans 24..56M)
//   [56,64M)  SLOT: wb_qkv(6M) -> vt(8M) -> wb_proj(2M) -> wb_w1(8M)
extern "C" void kernel_launch(void* const* d_in, const int* in_sizes, int n_in,
                              void* d_out, int out_size, void* d_ws, size_t ws_size,
                              hipStream_t stream) {
  const float* x      = (const float*)d_in[0];
  const float* ln1_g  = (const float*)d_in[1];
  const float* ln1_b  = (const float*)d_in[2];
  const float* qkv_w  = (const float*)d_in[3];
  const float* proj_w = (const float*)d_in[4];
  const float* proj_b = (const float*)d_in[5];
  const float* ln2_g  = (const float*)d_in[6];
  const float* ln2_b  = (const float*)d_in[7];
  const float* w1     = (const float*)d_in[8];
  const float* b1     = (const float*)d_in[9];
  const float* w2     = (const float*)d_in[10];
  const float* b2     = (const float*)d_in[11];
  float* out = (float*)d_out;                       // reference output dtype: float32

  char* ws = (char*)d_ws;
  float* x2   = (float*)ws;                        // 16 MB
  obf*   h    = (obf*)(ws + (16u << 20));          //  8 MB
  obf*   qkv  = (obf*)(ws + (24u << 20));          // 24 MB
  obf*   ao   = (obf*)(ws + (48u << 20));          //  8 MB
  obf*   m1   = (obf*)(ws + (24u << 20));          // 32 MB (overlays qkv+ao, both dead)
  __bf16* slot = (__bf16*)(ws + (56u << 20));      //  8 MB multi-use
  __bf16* wb_w2 = (__bf16*)(ws + (16u << 20));     //  8 MB (overlays h after it dies)

  const int M = 4096;

  // 0. wb_qkv = bf16(qkv_w)
  f2b_kernel<<<(3072 * 1024 / 8 + 255) / 256, 256, 0, stream>>>(qkv_w, slot, 3072 * 1024 / 8);
  // 1. LN1: x -> h
  ln_kernel<<<M, 256, 0, stream>>>(x, ln1_g, ln1_b, h);
  // 2. qkv = h @ qkv_w^T
  gemm_bt<EPI_NONE, 4><<<dim3(3072 / 128, M / 128), 256, 0, stream>>>(
      h, (const obf*)slot, qkv, nullptr, nullptr, M, 3072, 1024);
  // 3. vt = transpose(V)   (overwrites wb_qkv, now dead)
  vtrans_kernel<<<dim3(32, 32), 256, 0, stream>>>(qkv, (obf*)slot);
  // 4. attention -> ao   (512 blocks x 512 threads, 8 waves, XCD-swizzled)
  attn_kernel<<<512, 512, 0, stream>>>(qkv, (const obf*)slot, ao);
  // 5. wb_proj = bf16(proj_w)   (overwrites vt, now dead)
  f2b_kernel<<<(1024 * 1024 / 8 + 255) / 256, 256, 0, stream>>>(proj_w, slot, 1024 * 1024 / 8);
  // 6. x2 = x + ao @ proj_w^T + proj_b   (f32 out; BN=64 -> 512 blocks)
  gemm_bt<EPI_BIAS_RES_F32OUT, 2><<<dim3(1024 / 64, M / 128), 256, 0, stream>>>(
      ao, (const obf*)slot, x2, proj_b, x, M, 1024, 1024);
  // 7. LN2: x2 -> h
  ln_kernel<<<M, 256, 0, stream>>>(x2, ln2_g, ln2_b, h);
  // 8. wb_w1 = bf16(w1)   (overwrites wb_proj, now dead)
  f2b_kernel<<<(4096 * 1024 / 8 + 255) / 256, 256, 0, stream>>>(w1, slot, 4096 * 1024 / 8);
  // 9. m1 = gelu(h @ w1^T + b1)
  gemm_bt<EPI_BIAS_GELU, 4><<<dim3(4096 / 128, M / 128), 256, 0, stream>>>(
      h, (const obf*)slot, m1, b1, nullptr, M, 4096, 1024);
  // 10. wb_w2 = bf16(w2)   (overwrites h, now dead)
  f2b_kernel<<<(4096 * 1024 / 8 + 255) / 256, 256, 0, stream>>>(w2, wb_w2, 4096 * 1024 / 8);
  // 11. out = x2 + m1 @ w2^T + b2   (f32 out -> d_out; BN=64 -> 512 blocks)
  gemm_bt<EPI_BIAS_RESF32_F32OUT, 2><<<dim3(1024 / 64, M / 128), 256, 0, stream>>>(
      m1, (const obf*)wb_w2, out, b2, x2, M, 1024, 4096);
}

// Round 15
// 271.685 us; speedup vs baseline: 1.0131x; 1.0131x over previous
//
#include <hip/hip_runtime.h>
#include <hip/hip_bf16.h>

typedef __hip_bfloat16 obf;
typedef __attribute__((ext_vector_type(8))) __bf16 bf16x8;
typedef __attribute__((ext_vector_type(4))) float f32x4;

#define DEVINL __device__ __forceinline__

DEVINL void gload_lds16(const void* g, void* l) {
  __builtin_amdgcn_global_load_lds((const __attribute__((address_space(1))) void*)g,
                                   (__attribute__((address_space(3))) void*)l,
                                   16, 0, 0);
}

// ---------------- f32 -> bf16 conversion (weights) ----------------
__global__ void __launch_bounds__(256) f2b_kernel(const float* __restrict__ in,
                                                  __bf16* __restrict__ out, int n8)
{
  const int i = blockIdx.x * 256 + threadIdx.x;
  if (i >= n8) return;
  const float4 a = ((const float4*)in)[i * 2];
  const float4 b = ((const float4*)in)[i * 2 + 1];
  bf16x8 o;
  o[0] = (__bf16)a.x; o[1] = (__bf16)a.y; o[2] = (__bf16)a.z; o[3] = (__bf16)a.w;
  o[4] = (__bf16)b.x; o[5] = (__bf16)b.y; o[6] = (__bf16)b.z; o[7] = (__bf16)b.w;
  ((bf16x8*)out)[i] = o;
}

// ---------------- LayerNorm (one row per block, C=1024), f32 in -> bf16 out ----------------
__global__ void __launch_bounds__(256) ln_kernel(const float* __restrict__ xin,
    const float* __restrict__ g, const float* __restrict__ b, obf* __restrict__ out)
{
  const int row = blockIdx.x;
  const int t = threadIdx.x;
  const int lane = t & 63, w = t >> 6;
  float4 f = ((const float4*)xin)[(size_t)row * 256 + t];
  float v[4] = { f.x, f.y, f.z, f.w };
  float s1 = v[0] + v[1] + v[2] + v[3];
  float s2 = v[0]*v[0] + v[1]*v[1] + v[2]*v[2] + v[3]*v[3];
  #pragma unroll
  for (int off = 32; off >= 1; off >>= 1) {
    s1 += __shfl_xor(s1, off);
    s2 += __shfl_xor(s2, off);
  }
  __shared__ float red[8];
  if (lane == 0) { red[w] = s1; red[4 + w] = s2; }
  __syncthreads();
  s1 = red[0] + red[1] + red[2] + red[3];
  s2 = red[4] + red[5] + red[6] + red[7];
  const float mu = s1 * (1.f / 1024.f);
  const float var = s2 * (1.f / 1024.f) - mu * mu;
  const float rs = rsqrtf(var + 1e-5f);
  const float4 gv = ((const float4*)g)[t];
  const float4 bv = ((const float4*)b)[t];
  obf* op = out + (size_t)row * 1024 + t * 4;
  op[0] = __float2bfloat16((v[0] - mu) * rs * gv.x + bv.x);
  op[1] = __float2bfloat16((v[1] - mu) * rs * gv.y + bv.y);
  op[2] = __float2bfloat16((v[2] - mu) * rs * gv.z + bv.z);
  op[3] = __float2bfloat16((v[3] - mu) * rs * gv.w + bv.w);
}

// ---------------- GEMM: C[M,N] = A[M,K] @ W[N,K]^T (+ epilogue) ----------------
// ROUND-15: reverted to the round-13 single-buffer 2-barrier structure (32KB
// LDS, ~3.4 blocks/CU). Round-14's 64KB double-buffer halved occupancy and
// regressed (m132 lesson) — implicit wave-overlap at 3 blocks/CU beats
// explicit pipelining at 2 blocks/CU for this tile size.
enum { EPI_NONE = 0, EPI_BIAS_RES_F32OUT = 1, EPI_BIAS_GELU = 2, EPI_BIAS_RESF32_F32OUT = 3 };

template<int EPI, int NI>
__global__ void __launch_bounds__(256, 2) gemm_bt(
    const obf* __restrict__ A, const obf* __restrict__ Bw,
    void* __restrict__ Cout, const float* __restrict__ bias,
    const void* __restrict__ resid, int M, int N, int K)
{
  __shared__ __align__(16) char As[128 * 64 * 2];
  __shared__ __align__(16) char Bs[NI * 32 * 64 * 2];
  const int tid = threadIdx.x;
  const int lane = tid & 63;
  const int w = tid >> 6, wr = w >> 1, wc = w & 1;
  const int bm = blockIdx.y * 128, bn = blockIdx.x * (NI * 32);
  const size_t lda = (size_t)K * 2;

  f32x4 acc[4][NI];
  #pragma unroll
  for (int i = 0; i < 4; i++)
    #pragma unroll
    for (int j = 0; j < NI; j++) {
      acc[i][j][0] = 0.f; acc[i][j][1] = 0.f; acc[i][j][2] = 0.f; acc[i][j][3] = 0.f;
    }

  for (int k0 = 0; k0 < K; k0 += 64) {
    #pragma unroll
    for (int i = 0; i < 4; i++) {
      const int ci = tid + 256 * i;
      const int r = ci >> 3;
      const int gb = ((ci & 7) * 16) ^ ((r & 7) << 4);
      gload_lds16((const char*)A + (size_t)(bm + r) * lda + (size_t)k0 * 2 + gb, As + ci * 16);
    }
    #pragma unroll
    for (int i = 0; i < NI; i++) {
      const int ci = tid + 256 * i;
      const int r = ci >> 3;
      const int gb = ((ci & 7) * 16) ^ ((r & 7) << 4);
      gload_lds16((const char*)Bw + (size_t)(bn + r) * lda + (size_t)k0 * 2 + gb, Bs + ci * 16);
    }
    __syncthreads();

    bf16x8 af[4][2], bfr[NI][2];
    #pragma unroll
    for (int mi = 0; mi < 4; mi++) {
      const int r = wr * 64 + mi * 16 + (lane & 15);
      #pragma unroll
      for (int ks = 0; ks < 2; ks++) {
        const int cb = ks * 64 + ((lane >> 4) * 16);
        af[mi][ks] = *(const bf16x8*)(As + r * 128 + (cb ^ ((r & 7) << 4)));
      }
    }
    #pragma unroll
    for (int ni = 0; ni < NI; ni++) {
      const int r = wc * (NI * 16) + ni * 16 + (lane & 15);
      #pragma unroll
      for (int ks = 0; ks < 2; ks++) {
        const int cb = ks * 64 + ((lane >> 4) * 16);
        bfr[ni][ks] = *(const bf16x8*)(Bs + r * 128 + (cb ^ ((r & 7) << 4)));
      }
    }
    #pragma unroll
    for (int ks = 0; ks < 2; ks++)
      #pragma unroll
      for (int mi = 0; mi < 4; mi++)
        #pragma unroll
        for (int ni = 0; ni < NI; ni++)
          acc[mi][ni] = __builtin_amdgcn_mfma_f32_16x16x32_bf16(af[mi][ks], bfr[ni][ks], acc[mi][ni], 0, 0, 0);
    __syncthreads();
  }

  #pragma unroll
  for (int mi = 0; mi < 4; mi++) {
    #pragma unroll
    for (int ni = 0; ni < NI; ni++) {
      const int col = bn + wc * (NI * 16) + ni * 16 + (lane & 15);
      float bv = 0.f;
      if (EPI != EPI_NONE) bv = bias[col];
      #pragma unroll
      for (int r = 0; r < 4; r++) {
        const int row = bm + wr * 64 + mi * 16 + ((lane >> 4) << 2) + r;
        const float vacc = acc[mi][ni][r];
        const size_t idx = (size_t)row * N + col;
        if (EPI == EPI_NONE) {
          ((obf*)Cout)[idx] = __float2bfloat16(vacc);
        } else if (EPI == EPI_BIAS_RES_F32OUT) {
          const float x0 = ((const float*)resid)[idx];
          ((float*)Cout)[idx] = vacc + bv + x0;
        } else if (EPI == EPI_BIAS_GELU) {
          const float u = vacc + bv;
          ((obf*)Cout)[idx] = __float2bfloat16(0.5f * u * (1.f + erff(u * 0.70710678118f)));
        } else {   // EPI_BIAS_RESF32_F32OUT
          const float x0 = ((const float*)resid)[idx];
          ((float*)Cout)[idx] = vacc + bv + x0;
        }
      }
    }
  }
}

// ---------------- V transpose: vt[b][h][d][n] = qkv[b][n][2C + h*64 + d] ----------------
__global__ void __launch_bounds__(256) vtrans_kernel(const obf* __restrict__ qkv, obf* __restrict__ vt)
{
  const int bh = blockIdx.y;             // 0..31  (b*16+h)
  const int b = bh >> 4, h = bh & 15;
  const int n0 = blockIdx.x * 64;        // 32 tiles over N=2048
  __shared__ __bf16 tile[64][72];        // +8 pad
  const int t = threadIdx.x;
  {
    const int n = t >> 2;
    const int c0 = (t & 3) * 16;
    const __bf16* src = (const __bf16*)qkv + ((size_t)(b * 2048 + n0 + n)) * 3072 + 2048 + h * 64 + c0;
    bf16x8 u0 = *(const bf16x8*)src;
    bf16x8 u1 = *(const bf16x8*)(src + 8);
    #pragma unroll
    for (int j = 0; j < 8; j++) { tile[n][c0 + j] = u0[j]; tile[n][c0 + 8 + j] = u1[j]; }
  }
  __syncthreads();
  {
    const int d = t >> 2;
    const int c0 = (t & 3) * 16;
    bf16x8 o0, o1;
    #pragma unroll
    for (int j = 0; j < 8; j++) { o0[j] = tile[c0 + j][d]; o1[j] = tile[c0 + 8 + j][d]; }
    __bf16* dst = (__bf16*)vt + ((size_t)bh * 64 + d) * 2048 + n0 + c0;
    *(bf16x8*)dst = o0;
    *(bf16x8*)(dst + 8) = o1;
  }
}

// ---------------- Flash attention fwd ----------------
// ROUND-15: KV-tile 64 -> 128 at 8 waves / 512 threads, Q-tile 128.
// Halves the per-tile fixed costs (2 barrier drains + staging issue) from
// 32x to 16x with identical total MFMA and staging bytes. LDS 64KB:
// Ks 16K + Vs 16K + Ps 8x4K -> 2 blocks/CU = 16 waves/CU (same as round 13).
// No-max softmax, T14 reg prefetch, XCD swizzle retained.
__global__ void __launch_bounds__(512, 2) attn_kernel(
    const obf* __restrict__ qkv_, const obf* __restrict__ vt_, obf* __restrict__ ao)
{
  const __bf16* qkv = (const __bf16*)qkv_;
  const __bf16* vt  = (const __bf16*)vt_;
  const int bid = blockIdx.x;            // 0..511
  const int xcd = bid & 7, idx = bid >> 3;
  const int bh = xcd * 4 + (idx >> 4);   // 4 bh per XCD (K/V L2-resident)
  const int q0 = (idx & 15) * 128;
  const int b = bh >> 4, h = bh & 15;
  const int tid = threadIdx.x, lane = tid & 63, w = tid >> 6;   // w 0..7
  const int l15 = lane & 15, hi = lane >> 4;

  __shared__ __align__(16) char Ks[128 * 128];     // [kv=128][d=64]*2B, swizzled
  __shared__ __align__(16) char Vs[64 * 256];      // [d=64][kv=128]*2B, swizzled
  __shared__ __align__(16) char Ps[8 * 16 * 256];  // per-wave [16 q][128 kv]*2B, swz

  // Q fragments (A-operand: row=l15, k=hi*8..+7 per 32-k slice); wave = 16 q rows
  bf16x8 qf[2];
  {
    const int qrow = q0 + w * 16 + l15;
    #pragma unroll
    for (int ks = 0; ks < 2; ks++)
      qf[ks] = *(const bf16x8*)(qkv + ((size_t)(b * 2048 + qrow)) * 3072 + h * 64 + ks * 32 + hi * 8);
  }

  f32x4 o[4];
  #pragma unroll
  for (int j = 0; j < 4; j++) { o[j][0]=0.f; o[j][1]=0.f; o[j][2]=0.f; o[j][3]=0.f; }
  float lrow[4] = { 0.f, 0.f, 0.f, 0.f };

  const float kfac = 0.125f * 1.44269504089f;  // scale * log2(e)

  // ---- prologue: stage tile 0 (2 chunks/thread at 512 threads) ----
  bf16x8 pk[2], pv[2];
  #pragma unroll
  for (int i = 0; i < 2; i++) {
    const int ci = tid + 512 * i;
    const int kr = ci >> 3, kc = (ci & 7) * 8;
    pk[i] = *(const bf16x8*)(qkv + ((size_t)(b * 2048 + kr)) * 3072 + 1024 + h * 64 + kc);
    const int d = ci >> 4, vc = (ci & 15) * 8;
    pv[i] = *(const bf16x8*)(vt + ((size_t)bh * 64 + d) * 2048 + vc);
  }
  #pragma unroll
  for (int i = 0; i < 2; i++) {
    const int ci = tid + 512 * i;
    const int kr = ci >> 3, kcb = (ci & 7) * 16;
    *(bf16x8*)(Ks + kr * 128 + (kcb ^ ((kr & 7) << 4))) = pk[i];
    const int d = ci >> 4, vcb = (ci & 15) * 16;
    *(bf16x8*)(Vs + d * 256 + (vcb ^ ((d & 7) << 4))) = pv[i];
  }
  __syncthreads();

  for (int kt = 0; kt < 2048; kt += 128) {
    // ---- T14: issue next tile's loads (hidden under this tile's compute) ----
    if (kt + 128 < 2048) {
      #pragma unroll
      for (int i = 0; i < 2; i++) {
        const int ci = tid + 512 * i;
        const int kr = ci >> 3, kc = (ci & 7) * 8;
        pk[i] = *(const bf16x8*)(qkv + ((size_t)(b * 2048 + kt + 128 + kr)) * 3072 + 1024 + h * 64 + kc);
        const int d = ci >> 4, vc = (ci & 15) * 8;
        pv[i] = *(const bf16x8*)(vt + ((size_t)bh * 64 + d) * 2048 + kt + 128 + vc);
      }
    }

    // ---- S = Q K^T (16 q rows x 128 kv per wave) ----
    f32x4 s[8];
    #pragma unroll
    for (int j = 0; j < 8; j++) { s[j][0]=0.f; s[j][1]=0.f; s[j][2]=0.f; s[j][3]=0.f; }
    #pragma unroll
    for (int ni = 0; ni < 8; ni++) {
      const int r = ni * 16 + l15;
      const bf16x8 kf0 = *(const bf16x8*)(Ks + r * 128 + ((hi * 16) ^ ((r & 7) << 4)));
      const bf16x8 kf1 = *(const bf16x8*)(Ks + r * 128 + ((64 + hi * 16) ^ ((r & 7) << 4)));
      s[ni] = __builtin_amdgcn_mfma_f32_16x16x32_bf16(qf[0], kf0, s[ni], 0, 0, 0);
      s[ni] = __builtin_amdgcn_mfma_f32_16x16x32_bf16(qf[1], kf1, s[ni], 0, 0, 0);
    }

    // ---- no-max softmax: p = exp2(s*kfac); per-lane row-sum; P -> LDS ----
    #pragma unroll
    for (int r = 0; r < 4; r++) {
      const int qrl = (hi << 2) + r;
      char* psrow = Ps + w * 4096 + qrl * 256;
      float psum = 0.f;
      #pragma unroll
      for (int ni = 0; ni < 8; ni++) {
        const float p = exp2f(s[ni][r] * kfac);
        psum += p;
        *(__bf16*)(psrow + (((ni * 16 + l15) * 2) ^ ((qrl & 7) << 4))) = (__bf16)p;
      }
      lrow[r] += psum;
    }

    // ---- O += P V (K-dim 128 = 4 slices of 32) ----
    #pragma unroll
    for (int ks = 0; ks < 4; ks++) {
      const int rr = l15;
      const bf16x8 pa = *(const bf16x8*)(Ps + w * 4096 + rr * 256 + (((ks * 32 + hi * 8) * 2) ^ ((rr & 7) << 4)));
      #pragma unroll
      for (int df = 0; df < 4; df++) {
        const int dr = df * 16 + l15;
        const int cb = (ks * 32 + hi * 8) * 2;
        const bf16x8 vb = *(const bf16x8*)(Vs + dr * 256 + (cb ^ ((dr & 7) << 4)));
        o[df] = __builtin_amdgcn_mfma_f32_16x16x32_bf16(pa, vb, o[df], 0, 0, 0);
      }
    }

    __syncthreads();                 // all waves done reading Ks/Vs
    if (kt + 128 < 2048) {
      #pragma unroll
      for (int i = 0; i < 2; i++) {  // write prefetched tile
        const int ci = tid + 512 * i;
        const int kr = ci >> 3, kcb = (ci & 7) * 16;
        *(bf16x8*)(Ks + kr * 128 + (kcb ^ ((kr & 7) << 4))) = pk[i];
        const int d = ci >> 4, vcb = (ci & 15) * 16;
        *(bf16x8*)(Vs + d * 256 + (vcb ^ ((d & 7) << 4))) = pv[i];
      }
    }
    __syncthreads();                 // new tile visible
  }

  // ---- final row-sum reduce (within 16-lane groups) + write ----
  #pragma unroll
  for (int r = 0; r < 4; r++) {
    lrow[r] += __shfl_xor(lrow[r], 1);
    lrow[r] += __shfl_xor(lrow[r], 2);
    lrow[r] += __shfl_xor(lrow[r], 4);
    lrow[r] += __shfl_xor(lrow[r], 8);
  }
  #pragma unroll
  for (int r = 0; r < 4; r++) {
    const float inv = 1.f / lrow[r];
    const int qrow = q0 + w * 16 + (hi << 2) + r;
    #pragma unroll
    for (int df = 0; df < 4; df++) {
      const int col = h * 64 + df * 16 + l15;
      ao[((size_t)(b * 2048 + qrow)) * 1024 + col] = __float2bfloat16(o[df][r] * inv);
    }
  }
}

// ---------------- launch ----------------
// ws layout (64 MB total, slots time-multiplexed):
//   [ 0,16M)  x2   f32 [4096][1024]
//   [16,24M)  h    bf16 [4096][1024]          -> later wb_w2 (8MB) after h dies
//   [24,48M)  qkv  bf16 [4096][3072]          -> later part of m1
//   [48,56M)  ao   bf16 [4096][1024]          -> later part of m1 (m1 spans 24..56M)
//   [56,64M)  SLOT: wb_qkv(6M) -> vt(8M) -> wb_proj(2M) -> wb_w1(8M)
extern "C" void kernel_launch(void* const* d_in, const int* in_sizes, int n_in,
                              void* d_out, int out_size, void* d_ws, size_t ws_size,
                              hipStream_t stream) {
  const float* x      = (const float*)d_in[0];
  const float* ln1_g  = (const float*)d_in[1];
  const float* ln1_b  = (const float*)d_in[2];
  const float* qkv_w  = (const float*)d_in[3];
  const float* proj_w = (const float*)d_in[4];
  const float* proj_b = (const float*)d_in[5];
  const float* ln2_g  = (const float*)d_in[6];
  const float* ln2_b  = (const float*)d_in[7];
  const float* w1     = (const float*)d_in[8];
  const float* b1     = (const float*)d_in[9];
  const float* w2     = (const float*)d_in[10];
  const float* b2     = (const float*)d_in[11];
  float* out = (float*)d_out;                       // reference output dtype: float32

  char* ws = (char*)d_ws;
  float* x2   = (float*)ws;                        // 16 MB
  obf*   h    = (obf*)(ws + (16u << 20));          //  8 MB
  obf*   qkv  = (obf*)(ws + (24u << 20));          // 24 MB
  obf*   ao   = (obf*)(ws + (48u << 20));          //  8 MB
  obf*   m1   = (obf*)(ws + (24u << 20));          // 32 MB (overlays qkv+ao, both dead)
  __bf16* slot = (__bf16*)(ws + (56u << 20));      //  8 MB multi-use
  __bf16* wb_w2 = (__bf16*)(ws + (16u << 20));     //  8 MB (overlays h after it dies)

  const int M = 4096;

  // 0. wb_qkv = bf16(qkv_w)
  f2b_kernel<<<(3072 * 1024 / 8 + 255) / 256, 256, 0, stream>>>(qkv_w, slot, 3072 * 1024 / 8);
  // 1. LN1: x -> h
  ln_kernel<<<M, 256, 0, stream>>>(x, ln1_g, ln1_b, h);
  // 2. qkv = h @ qkv_w^T
  gemm_bt<EPI_NONE, 4><<<dim3(3072 / 128, M / 128), 256, 0, stream>>>(
      h, (const obf*)slot, qkv, nullptr, nullptr, M, 3072, 1024);
  // 3. vt = transpose(V)   (overwrites wb_qkv, now dead)
  vtrans_kernel<<<dim3(32, 32), 256, 0, stream>>>(qkv, (obf*)slot);
  // 4. attention -> ao   (512 blocks x 512 threads, KV=128, XCD-swizzled)
  attn_kernel<<<512, 512, 0, stream>>>(qkv, (const obf*)slot, ao);
  // 5. wb_proj = bf16(proj_w)   (overwrites vt, now dead)
  f2b_kernel<<<(1024 * 1024 / 8 + 255) / 256, 256, 0, stream>>>(proj_w, slot, 1024 * 1024 / 8);
  // 6. x2 = x + ao @ proj_w^T + proj_b   (f32 out; BN=64 -> 512 blocks)
  gemm_bt<EPI_BIAS_RES_F32OUT, 2><<<dim3(1024 / 64, M / 128), 256, 0, stream>>>(
      ao, (const obf*)slot, x2, proj_b, x, M, 1024, 1024);
  // 7. LN2: x2 -> h
  ln_kernel<<<M, 256, 0, stream>>>(x2, ln2_g, ln2_b, h);
  // 8. wb_w1 = bf16(w1)   (overwrites wb_proj, now dead)
  f2b_kernel<<<(4096 * 1024 / 8 + 255) / 256, 256, 0, stream>>>(w1, slot, 4096 * 1024 / 8);
  // 9. m1 = gelu(h @ w1^T + b1)
  gemm_bt<EPI_BIAS_GELU, 4><<<dim3(4096 / 128, M / 128), 256, 0, stream>>>(
      h, (const obf*)slot, m1, b1, nullptr, M, 4096, 1024);
  // 10. wb_w2 = bf16(w2)   (overwrites h, now dead)
  f2b_kernel<<<(4096 * 1024 / 8 + 255) / 256, 256, 0, stream>>>(w2, wb_w2, 4096 * 1024 / 8);
  // 11. out = x2 + m1 @ w2^T + b2   (f32 out -> d_out; BN=64 -> 512 blocks)
  gemm_bt<EPI_BIAS_RESF32_F32OUT, 2><<<dim3(1024 / 64, M / 128), 256, 0, stream>>>(
      m1, (const obf*)wb_w2, out, b2, x2, M, 1024, 4096);
}

// Round 16
// 252.485 us; speedup vs baseline: 1.0902x; 1.0760x over previous
//
#include <hip/hip_runtime.h>
#include <hip/hip_bf16.h>

typedef __hip_bfloat16 obf;
typedef __attribute__((ext_vector_type(8))) __bf16 bf16x8;
typedef __attribute__((ext_vector_type(4))) float f32x4;

#define DEVINL __device__ __forceinline__

DEVINL void gload_lds16(const void* g, void* l) {
  __builtin_amdgcn_global_load_lds((const __attribute__((address_space(1))) void*)g,
                                   (__attribute__((address_space(3))) void*)l,
                                   16, 0, 0);
}

// ---------------- f32 -> bf16 conversion (weights) ----------------
__global__ void __launch_bounds__(256) f2b_kernel(const float* __restrict__ in,
                                                  __bf16* __restrict__ out, int n8)
{
  const int i = blockIdx.x * 256 + threadIdx.x;
  if (i >= n8) return;
  const float4 a = ((const float4*)in)[i * 2];
  const float4 b = ((const float4*)in)[i * 2 + 1];
  bf16x8 o;
  o[0] = (__bf16)a.x; o[1] = (__bf16)a.y; o[2] = (__bf16)a.z; o[3] = (__bf16)a.w;
  o[4] = (__bf16)b.x; o[5] = (__bf16)b.y; o[6] = (__bf16)b.z; o[7] = (__bf16)b.w;
  ((bf16x8*)out)[i] = o;
}

// ---------------- LayerNorm (one row per block, C=1024), f32 in -> bf16 out ----------------
__global__ void __launch_bounds__(256) ln_kernel(const float* __restrict__ xin,
    const float* __restrict__ g, const float* __restrict__ b, obf* __restrict__ out)
{
  const int row = blockIdx.x;
  const int t = threadIdx.x;
  const int lane = t & 63, w = t >> 6;
  float4 f = ((const float4*)xin)[(size_t)row * 256 + t];
  float v[4] = { f.x, f.y, f.z, f.w };
  float s1 = v[0] + v[1] + v[2] + v[3];
  float s2 = v[0]*v[0] + v[1]*v[1] + v[2]*v[2] + v[3]*v[3];
  #pragma unroll
  for (int off = 32; off >= 1; off >>= 1) {
    s1 += __shfl_xor(s1, off);
    s2 += __shfl_xor(s2, off);
  }
  __shared__ float red[8];
  if (lane == 0) { red[w] = s1; red[4 + w] = s2; }
  __syncthreads();
  s1 = red[0] + red[1] + red[2] + red[3];
  s2 = red[4] + red[5] + red[6] + red[7];
  const float mu = s1 * (1.f / 1024.f);
  const float var = s2 * (1.f / 1024.f) - mu * mu;
  const float rs = rsqrtf(var + 1e-5f);
  const float4 gv = ((const float4*)g)[t];
  const float4 bv = ((const float4*)b)[t];
  obf* op = out + (size_t)row * 1024 + t * 4;
  op[0] = __float2bfloat16((v[0] - mu) * rs * gv.x + bv.x);
  op[1] = __float2bfloat16((v[1] - mu) * rs * gv.y + bv.y);
  op[2] = __float2bfloat16((v[2] - mu) * rs * gv.z + bv.z);
  op[3] = __float2bfloat16((v[3] - mu) * rs * gv.w + bv.w);
}

// ---------------- GEMM: C[M,N] = A[M,K] @ W[N,K]^T (+ epilogue) ----------------
// Round-13 single-buffer 2-barrier structure (32KB LDS, ~3.4 blocks/CU) —
// verified fastest of the variants tried (r14 64KB dbuf regressed, m132).
enum { EPI_NONE = 0, EPI_BIAS_RES_F32OUT = 1, EPI_BIAS_GELU = 2, EPI_BIAS_RESF32_F32OUT = 3 };

template<int EPI, int NI>
__global__ void __launch_bounds__(256, 2) gemm_bt(
    const obf* __restrict__ A, const obf* __restrict__ Bw,
    void* __restrict__ Cout, const float* __restrict__ bias,
    const void* __restrict__ resid, int M, int N, int K)
{
  __shared__ __align__(16) char As[128 * 64 * 2];
  __shared__ __align__(16) char Bs[NI * 32 * 64 * 2];
  const int tid = threadIdx.x;
  const int lane = tid & 63;
  const int w = tid >> 6, wr = w >> 1, wc = w & 1;
  const int bm = blockIdx.y * 128, bn = blockIdx.x * (NI * 32);
  const size_t lda = (size_t)K * 2;

  f32x4 acc[4][NI];
  #pragma unroll
  for (int i = 0; i < 4; i++)
    #pragma unroll
    for (int j = 0; j < NI; j++) {
      acc[i][j][0] = 0.f; acc[i][j][1] = 0.f; acc[i][j][2] = 0.f; acc[i][j][3] = 0.f;
    }

  for (int k0 = 0; k0 < K; k0 += 64) {
    #pragma unroll
    for (int i = 0; i < 4; i++) {
      const int ci = tid + 256 * i;
      const int r = ci >> 3;
      const int gb = ((ci & 7) * 16) ^ ((r & 7) << 4);
      gload_lds16((const char*)A + (size_t)(bm + r) * lda + (size_t)k0 * 2 + gb, As + ci * 16);
    }
    #pragma unroll
    for (int i = 0; i < NI; i++) {
      const int ci = tid + 256 * i;
      const int r = ci >> 3;
      const int gb = ((ci & 7) * 16) ^ ((r & 7) << 4);
      gload_lds16((const char*)Bw + (size_t)(bn + r) * lda + (size_t)k0 * 2 + gb, Bs + ci * 16);
    }
    __syncthreads();

    bf16x8 af[4][2], bfr[NI][2];
    #pragma unroll
    for (int mi = 0; mi < 4; mi++) {
      const int r = wr * 64 + mi * 16 + (lane & 15);
      #pragma unroll
      for (int ks = 0; ks < 2; ks++) {
        const int cb = ks * 64 + ((lane >> 4) * 16);
        af[mi][ks] = *(const bf16x8*)(As + r * 128 + (cb ^ ((r & 7) << 4)));
      }
    }
    #pragma unroll
    for (int ni = 0; ni < NI; ni++) {
      const int r = wc * (NI * 16) + ni * 16 + (lane & 15);
      #pragma unroll
      for (int ks = 0; ks < 2; ks++) {
        const int cb = ks * 64 + ((lane >> 4) * 16);
        bfr[ni][ks] = *(const bf16x8*)(Bs + r * 128 + (cb ^ ((r & 7) << 4)));
      }
    }
    #pragma unroll
    for (int ks = 0; ks < 2; ks++)
      #pragma unroll
      for (int mi = 0; mi < 4; mi++)
        #pragma unroll
        for (int ni = 0; ni < NI; ni++)
          acc[mi][ni] = __builtin_amdgcn_mfma_f32_16x16x32_bf16(af[mi][ks], bfr[ni][ks], acc[mi][ni], 0, 0, 0);
    __syncthreads();
  }

  #pragma unroll
  for (int mi = 0; mi < 4; mi++) {
    #pragma unroll
    for (int ni = 0; ni < NI; ni++) {
      const int col = bn + wc * (NI * 16) + ni * 16 + (lane & 15);
      float bv = 0.f;
      if (EPI != EPI_NONE) bv = bias[col];
      #pragma unroll
      for (int r = 0; r < 4; r++) {
        const int row = bm + wr * 64 + mi * 16 + ((lane >> 4) << 2) + r;
        const float vacc = acc[mi][ni][r];
        const size_t idx = (size_t)row * N + col;
        if (EPI == EPI_NONE) {
          ((obf*)Cout)[idx] = __float2bfloat16(vacc);
        } else if (EPI == EPI_BIAS_RES_F32OUT) {
          const float x0 = ((const float*)resid)[idx];
          ((float*)Cout)[idx] = vacc + bv + x0;
        } else if (EPI == EPI_BIAS_GELU) {
          const float u = vacc + bv;
          ((obf*)Cout)[idx] = __float2bfloat16(0.5f * u * (1.f + erff(u * 0.70710678118f)));
        } else {   // EPI_BIAS_RESF32_F32OUT
          const float x0 = ((const float*)resid)[idx];
          ((float*)Cout)[idx] = vacc + bv + x0;
        }
      }
    }
  }
}

// ---------------- V transpose: vt[b][h][d][n] = qkv[b][n][2C + h*64 + d] ----------------
__global__ void __launch_bounds__(256) vtrans_kernel(const obf* __restrict__ qkv, obf* __restrict__ vt)
{
  const int bh = blockIdx.y;             // 0..31  (b*16+h)
  const int b = bh >> 4, h = bh & 15;
  const int n0 = blockIdx.x * 64;        // 32 tiles over N=2048
  __shared__ __bf16 tile[64][72];        // +8 pad
  const int t = threadIdx.x;
  {
    const int n = t >> 2;
    const int c0 = (t & 3) * 16;
    const __bf16* src = (const __bf16*)qkv + ((size_t)(b * 2048 + n0 + n)) * 3072 + 2048 + h * 64 + c0;
    bf16x8 u0 = *(const bf16x8*)src;
    bf16x8 u1 = *(const bf16x8*)(src + 8);
    #pragma unroll
    for (int j = 0; j < 8; j++) { tile[n][c0 + j] = u0[j]; tile[n][c0 + 8 + j] = u1[j]; }
  }
  __syncthreads();
  {
    const int d = t >> 2;
    const int c0 = (t & 3) * 16;
    bf16x8 o0, o1;
    #pragma unroll
    for (int j = 0; j < 8; j++) { o0[j] = tile[c0 + j][d]; o1[j] = tile[c0 + 8 + j][d]; }
    __bf16* dst = (__bf16*)vt + ((size_t)bh * 64 + d) * 2048 + n0 + c0;
    *(bf16x8*)dst = o0;
    *(bf16x8*)(dst + 8) = o1;
  }
}

// ---------------- Flash attention fwd ----------------
// ROUND-16: round-13 geometry (KV=64, 8 waves / 512 threads, Q-tile 128,
// no-max softmax, XCD swizzle) + double-buffered Ks/Vs with ONE barrier per
// tile. Phase t: [issue loads(t+1) -> regs | compute buf[cur] | ds_write
// regs -> buf[cur^1] | sync]. The sync at end of t guarantees (a) t's reads
// of buf[cur] done before t+1 overwrites it, (b) t's writes to buf[cur^1]
// visible for t+1's compute (compiler drains lgkm before s_barrier).
// LDS 48KB: Ks 2x8K + Vs 2x8K + Ps 16K (grid-limited 2 blocks/CU anyway).
__global__ void __launch_bounds__(512, 2) attn_kernel(
    const obf* __restrict__ qkv_, const obf* __restrict__ vt_, obf* __restrict__ ao)
{
  const __bf16* qkv = (const __bf16*)qkv_;
  const __bf16* vt  = (const __bf16*)vt_;
  const int bid = blockIdx.x;            // 0..511
  const int xcd = bid & 7, idx = bid >> 3;
  const int bh = xcd * 4 + (idx >> 4);   // 4 bh per XCD (K/V L2-resident)
  const int q0 = (idx & 15) * 128;
  const int b = bh >> 4, h = bh & 15;
  const int tid = threadIdx.x, lane = tid & 63, w = tid >> 6;   // w 0..7
  const int l15 = lane & 15, hi = lane >> 4;

  __shared__ __align__(16) char Ks[2][64 * 128];   // [kv=64][d=64]*2B, swizzled
  __shared__ __align__(16) char Vs[2][64 * 128];   // [d=64][kv=64]*2B, swizzled
  __shared__ __align__(16) char Ps[8 * 16 * 128];  // per-wave [16 q][64 kv]*2B, swz

  // Q fragments (A-operand: row=l15, k=hi*8..+7 per 32-k slice); wave = 16 q rows
  bf16x8 qf[2];
  {
    const int qrow = q0 + w * 16 + l15;
    #pragma unroll
    for (int ks = 0; ks < 2; ks++)
      qf[ks] = *(const bf16x8*)(qkv + ((size_t)(b * 2048 + qrow)) * 3072 + h * 64 + ks * 32 + hi * 8);
  }

  f32x4 o[4];
  #pragma unroll
  for (int j = 0; j < 4; j++) { o[j][0]=0.f; o[j][1]=0.f; o[j][2]=0.f; o[j][3]=0.f; }
  float lrow[4] = { 0.f, 0.f, 0.f, 0.f };

  const float kfac = 0.125f * 1.44269504089f;  // scale * log2(e)

  const int kr = tid >> 3, kc = (tid & 7) * 8;   // staging coords (1 chunk/thread)
  const int kcb = (tid & 7) * 16;
  const int kswz = kcb ^ ((kr & 7) << 4);

  // ---- prologue: stage tile 0 into buf 0 ----
  bf16x8 pk, pv;
  pk = *(const bf16x8*)(qkv + ((size_t)(b * 2048 + kr)) * 3072 + 1024 + h * 64 + kc);
  pv = *(const bf16x8*)(vt + ((size_t)bh * 64 + kr) * 2048 + kc);
  *(bf16x8*)(Ks[0] + kr * 128 + kswz) = pk;
  *(bf16x8*)(Vs[0] + kr * 128 + kswz) = pv;
  __syncthreads();

  for (int kt = 0; kt < 2048; kt += 64) {
    const int cur = (kt >> 6) & 1;
    // ---- issue next tile's loads (in flight across the whole compute phase) ----
    if (kt + 64 < 2048) {
      pk = *(const bf16x8*)(qkv + ((size_t)(b * 2048 + kt + 64 + kr)) * 3072 + 1024 + h * 64 + kc);
      pv = *(const bf16x8*)(vt + ((size_t)bh * 64 + kr) * 2048 + kt + 64 + kc);
    }

    // ---- S = Q K^T (16 q rows x 64 kv per wave) ----
    f32x4 s[4];
    #pragma unroll
    for (int j = 0; j < 4; j++) { s[j][0]=0.f; s[j][1]=0.f; s[j][2]=0.f; s[j][3]=0.f; }
    #pragma unroll
    for (int ni = 0; ni < 4; ni++) {
      const int r = ni * 16 + l15;
      const bf16x8 kf0 = *(const bf16x8*)(Ks[cur] + r * 128 + ((hi * 16) ^ ((r & 7) << 4)));
      const bf16x8 kf1 = *(const bf16x8*)(Ks[cur] + r * 128 + ((64 + hi * 16) ^ ((r & 7) << 4)));
      s[ni] = __builtin_amdgcn_mfma_f32_16x16x32_bf16(qf[0], kf0, s[ni], 0, 0, 0);
      s[ni] = __builtin_amdgcn_mfma_f32_16x16x32_bf16(qf[1], kf1, s[ni], 0, 0, 0);
    }

    // ---- no-max softmax: p = exp2(s*kfac); per-lane row-sum; P -> LDS ----
    #pragma unroll
    for (int r = 0; r < 4; r++) {
      const int qrl = (hi << 2) + r;
      char* psrow = Ps + w * 2048 + qrl * 128;
      float psum = 0.f;
      #pragma unroll
      for (int ni = 0; ni < 4; ni++) {
        const float p = exp2f(s[ni][r] * kfac);
        psum += p;
        *(__bf16*)(psrow + (((ni * 16 + l15) * 2) ^ ((qrl & 7) << 4))) = (__bf16)p;
      }
      lrow[r] += psum;
    }

    // ---- O += P V ----
    #pragma unroll
    for (int ks = 0; ks < 2; ks++) {
      const int rr = l15;
      const bf16x8 pa = *(const bf16x8*)(Ps + w * 2048 + rr * 128 + (((ks * 32 + hi * 8) * 2) ^ ((rr & 7) << 4)));
      #pragma unroll
      for (int df = 0; df < 4; df++) {
        const int dr = df * 16 + l15;
        const int cb = (ks * 32 + hi * 8) * 2;
        const bf16x8 vb = *(const bf16x8*)(Vs[cur] + dr * 128 + (cb ^ ((dr & 7) << 4)));
        o[df] = __builtin_amdgcn_mfma_f32_16x16x32_bf16(pa, vb, o[df], 0, 0, 0);
      }
    }

    // ---- write prefetched tile to the other buffer, then ONE barrier ----
    if (kt + 64 < 2048) {
      *(bf16x8*)(Ks[cur ^ 1] + kr * 128 + kswz) = pk;
      *(bf16x8*)(Vs[cur ^ 1] + kr * 128 + kswz) = pv;
    }
    __syncthreads();
  }

  // ---- final row-sum reduce (within 16-lane groups) + write ----
  #pragma unroll
  for (int r = 0; r < 4; r++) {
    lrow[r] += __shfl_xor(lrow[r], 1);
    lrow[r] += __shfl_xor(lrow[r], 2);
    lrow[r] += __shfl_xor(lrow[r], 4);
    lrow[r] += __shfl_xor(lrow[r], 8);
  }
  #pragma unroll
  for (int r = 0; r < 4; r++) {
    const float inv = 1.f / lrow[r];
    const int qrow = q0 + w * 16 + (hi << 2) + r;
    #pragma unroll
    for (int df = 0; df < 4; df++) {
      const int col = h * 64 + df * 16 + l15;
      ao[((size_t)(b * 2048 + qrow)) * 1024 + col] = __float2bfloat16(o[df][r] * inv);
    }
  }
}

// ---------------- launch ----------------
// ws layout (64 MB total, slots time-multiplexed):
//   [ 0,16M)  x2   f32 [4096][1024]
//   [16,24M)  h    bf16 [4096][1024]          -> later wb_w2 (8MB) after h dies
//   [24,48M)  qkv  bf16 [4096][3072]          -> later part of m1
//   [48,56M)  ao   bf16 [4096][1024]          -> later part of m1 (m1 spans 24..56M)
//   [56,64M)  SLOT: wb_qkv(6M) -> vt(8M) -> wb_proj(2M) -> wb_w1(8M)
extern "C" void kernel_launch(void* const* d_in, const int* in_sizes, int n_in,
                              void* d_out, int out_size, void* d_ws, size_t ws_size,
                              hipStream_t stream) {
  const float* x      = (const float*)d_in[0];
  const float* ln1_g  = (const float*)d_in[1];
  const float* ln1_b  = (const float*)d_in[2];
  const float* qkv_w  = (const float*)d_in[3];
  const float* proj_w = (const float*)d_in[4];
  const float* proj_b = (const float*)d_in[5];
  const float* ln2_g  = (const float*)d_in[6];
  const float* ln2_b  = (const float*)d_in[7];
  const float* w1     = (const float*)d_in[8];
  const float* b1     = (const float*)d_in[9];
  const float* w2     = (const float*)d_in[10];
  const float* b2     = (const float*)d_in[11];
  float* out = (float*)d_out;                       // reference output dtype: float32

  char* ws = (char*)d_ws;
  float* x2   = (float*)ws;                        // 16 MB
  obf*   h    = (obf*)(ws + (16u << 20));          //  8 MB
  obf*   qkv  = (obf*)(ws + (24u << 20));          // 24 MB
  obf*   ao   = (obf*)(ws + (48u << 20));          //  8 MB
  obf*   m1   = (obf*)(ws + (24u << 20));          // 32 MB (overlays qkv+ao, both dead)
  __bf16* slot = (__bf16*)(ws + (56u << 20));      //  8 MB multi-use
  __bf16* wb_w2 = (__bf16*)(ws + (16u << 20));     //  8 MB (overlays h after it dies)

  const int M = 4096;

  // 0. wb_qkv = bf16(qkv_w)
  f2b_kernel<<<(3072 * 1024 / 8 + 255) / 256, 256, 0, stream>>>(qkv_w, slot, 3072 * 1024 / 8);
  // 1. LN1: x -> h
  ln_kernel<<<M, 256, 0, stream>>>(x, ln1_g, ln1_b, h);
  // 2. qkv = h @ qkv_w^T
  gemm_bt<EPI_NONE, 4><<<dim3(3072 / 128, M / 128), 256, 0, stream>>>(
      h, (const obf*)slot, qkv, nullptr, nullptr, M, 3072, 1024);
  // 3. vt = transpose(V)   (overwrites wb_qkv, now dead)
  vtrans_kernel<<<dim3(32, 32), 256, 0, stream>>>(qkv, (obf*)slot);
  // 4. attention -> ao   (512 blocks x 512 threads, KV=64 dbuf 1-barrier)
  attn_kernel<<<512, 512, 0, stream>>>(qkv, (const obf*)slot, ao);
  // 5. wb_proj = bf16(proj_w)   (overwrites vt, now dead)
  f2b_kernel<<<(1024 * 1024 / 8 + 255) / 256, 256, 0, stream>>>(proj_w, slot, 1024 * 1024 / 8);
  // 6. x2 = x + ao @ proj_w^T + proj_b   (f32 out; BN=64 -> 512 blocks)
  gemm_bt<EPI_BIAS_RES_F32OUT, 2><<<dim3(1024 / 64, M / 128), 256, 0, stream>>>(
      ao, (const obf*)slot, x2, proj_b, x, M, 1024, 1024);
  // 7. LN2: x2 -> h
  ln_kernel<<<M, 256, 0, stream>>>(x2, ln2_g, ln2_b, h);
  // 8. wb_w1 = bf16(w1)   (overwrites wb_proj, now dead)
  f2b_kernel<<<(4096 * 1024 / 8 + 255) / 256, 256, 0, stream>>>(w1, slot, 4096 * 1024 / 8);
  // 9. m1 = gelu(h @ w1^T + b1)
  gemm_bt<EPI_BIAS_GELU, 4><<<dim3(4096 / 128, M / 128), 256, 0, stream>>>(
      h, (const obf*)slot, m1, b1, nullptr, M, 4096, 1024);
  // 10. wb_w2 = bf16(w2)   (overwrites h, now dead)
  f2b_kernel<<<(4096 * 1024 / 8 + 255) / 256, 256, 0, stream>>>(w2, wb_w2, 4096 * 1024 / 8);
  // 11. out = x2 + m1 @ w2^T + b2   (f32 out -> d_out; BN=64 -> 512 blocks)
  gemm_bt<EPI_BIAS_RESF32_F32OUT, 2><<<dim3(1024 / 64, M / 128), 256, 0, stream>>>(
      m1, (const obf*)wb_w2, out, b2, x2, M, 1024, 4096);
}

// Round 17
// 251.269 us; speedup vs baseline: 1.0954x; 1.0048x over previous
//
#include <hip/hip_runtime.h>
#include <hip/hip_bf16.h>

typedef __hip_bfloat16 obf;
typedef __attribute__((ext_vector_type(8))) __bf16 bf16x8;
typedef __attribute__((ext_vector_type(4))) float f32x4;

#define DEVINL __device__ __forceinline__

DEVINL void gload_lds16(const void* g, void* l) {
  __builtin_amdgcn_global_load_lds((const __attribute__((address_space(1))) void*)g,
                                   (__attribute__((address_space(3))) void*)l,
                                   16, 0, 0);
}

// ---------------- f32 -> bf16 conversion (weights) ----------------
__global__ void __launch_bounds__(256) f2b_kernel(const float* __restrict__ in,
                                                  __bf16* __restrict__ out, int n8)
{
  const int i = blockIdx.x * 256 + threadIdx.x;
  if (i >= n8) return;
  const float4 a = ((const float4*)in)[i * 2];
  const float4 b = ((const float4*)in)[i * 2 + 1];
  bf16x8 o;
  o[0] = (__bf16)a.x; o[1] = (__bf16)a.y; o[2] = (__bf16)a.z; o[3] = (__bf16)a.w;
  o[4] = (__bf16)b.x; o[5] = (__bf16)b.y; o[6] = (__bf16)b.z; o[7] = (__bf16)b.w;
  ((bf16x8*)out)[i] = o;
}

// ---------------- LayerNorm (one row per block, C=1024), f32 in -> bf16 out ----------------
__global__ void __launch_bounds__(256) ln_kernel(const float* __restrict__ xin,
    const float* __restrict__ g, const float* __restrict__ b, obf* __restrict__ out)
{
  const int row = blockIdx.x;
  const int t = threadIdx.x;
  const int lane = t & 63, w = t >> 6;
  float4 f = ((const float4*)xin)[(size_t)row * 256 + t];
  float v[4] = { f.x, f.y, f.z, f.w };
  float s1 = v[0] + v[1] + v[2] + v[3];
  float s2 = v[0]*v[0] + v[1]*v[1] + v[2]*v[2] + v[3]*v[3];
  #pragma unroll
  for (int off = 32; off >= 1; off >>= 1) {
    s1 += __shfl_xor(s1, off);
    s2 += __shfl_xor(s2, off);
  }
  __shared__ float red[8];
  if (lane == 0) { red[w] = s1; red[4 + w] = s2; }
  __syncthreads();
  s1 = red[0] + red[1] + red[2] + red[3];
  s2 = red[4] + red[5] + red[6] + red[7];
  const float mu = s1 * (1.f / 1024.f);
  const float var = s2 * (1.f / 1024.f) - mu * mu;
  const float rs = rsqrtf(var + 1e-5f);
  const float4 gv = ((const float4*)g)[t];
  const float4 bv = ((const float4*)b)[t];
  obf* op = out + (size_t)row * 1024 + t * 4;
  op[0] = __float2bfloat16((v[0] - mu) * rs * gv.x + bv.x);
  op[1] = __float2bfloat16((v[1] - mu) * rs * gv.y + bv.y);
  op[2] = __float2bfloat16((v[2] - mu) * rs * gv.z + bv.z);
  op[3] = __float2bfloat16((v[3] - mu) * rs * gv.w + bv.w);
}

// ---------------- GEMM: C[M,N] = A[M,K] @ W[N,K]^T (+ epilogue) ----------------
// Round-13 single-buffer 2-barrier structure (fastest variant measured).
// ROUND-17: bijective XCD swizzle (T1, m204 form) — each XCD gets a contiguous
// row-major chunk of blocks so A-panels stay resident in its private L2.
// All grids divisible by 8 (1024/768/512/512).
enum { EPI_NONE = 0, EPI_BIAS_RES_F32OUT = 1, EPI_BIAS_GELU = 2, EPI_BIAS_RESF32_F32OUT = 3 };

template<int EPI, int NI>
__global__ void __launch_bounds__(256, 2) gemm_bt(
    const obf* __restrict__ A, const obf* __restrict__ Bw,
    void* __restrict__ Cout, const float* __restrict__ bias,
    const void* __restrict__ resid, int M, int N, int K)
{
  __shared__ __align__(16) char As[128 * 64 * 2];
  __shared__ __align__(16) char Bs[NI * 32 * 64 * 2];
  const int tid = threadIdx.x;
  const int lane = tid & 63;
  const int w = tid >> 6, wr = w >> 1, wc = w & 1;

  // T1 bijective XCD swizzle: flat dispatch id -> contiguous chunk per XCD
  const int flat = blockIdx.y * gridDim.x + blockIdx.x;
  const int chunk = (gridDim.x * gridDim.y) >> 3;      // grids all %8==0
  const int wg = (flat & 7) * chunk + (flat >> 3);
  const int bx = wg % gridDim.x, by = wg / gridDim.x;

  const int bm = by * 128, bn = bx * (NI * 32);
  const size_t lda = (size_t)K * 2;

  f32x4 acc[4][NI];
  #pragma unroll
  for (int i = 0; i < 4; i++)
    #pragma unroll
    for (int j = 0; j < NI; j++) {
      acc[i][j][0] = 0.f; acc[i][j][1] = 0.f; acc[i][j][2] = 0.f; acc[i][j][3] = 0.f;
    }

  for (int k0 = 0; k0 < K; k0 += 64) {
    #pragma unroll
    for (int i = 0; i < 4; i++) {
      const int ci = tid + 256 * i;
      const int r = ci >> 3;
      const int gb = ((ci & 7) * 16) ^ ((r & 7) << 4);
      gload_lds16((const char*)A + (size_t)(bm + r) * lda + (size_t)k0 * 2 + gb, As + ci * 16);
    }
    #pragma unroll
    for (int i = 0; i < NI; i++) {
      const int ci = tid + 256 * i;
      const int r = ci >> 3;
      const int gb = ((ci & 7) * 16) ^ ((r & 7) << 4);
      gload_lds16((const char*)Bw + (size_t)(bn + r) * lda + (size_t)k0 * 2 + gb, Bs + ci * 16);
    }
    __syncthreads();

    bf16x8 af[4][2], bfr[NI][2];
    #pragma unroll
    for (int mi = 0; mi < 4; mi++) {
      const int r = wr * 64 + mi * 16 + (lane & 15);
      #pragma unroll
      for (int ks = 0; ks < 2; ks++) {
        const int cb = ks * 64 + ((lane >> 4) * 16);
        af[mi][ks] = *(const bf16x8*)(As + r * 128 + (cb ^ ((r & 7) << 4)));
      }
    }
    #pragma unroll
    for (int ni = 0; ni < NI; ni++) {
      const int r = wc * (NI * 16) + ni * 16 + (lane & 15);
      #pragma unroll
      for (int ks = 0; ks < 2; ks++) {
        const int cb = ks * 64 + ((lane >> 4) * 16);
        bfr[ni][ks] = *(const bf16x8*)(Bs + r * 128 + (cb ^ ((r & 7) << 4)));
      }
    }
    #pragma unroll
    for (int ks = 0; ks < 2; ks++)
      #pragma unroll
      for (int mi = 0; mi < 4; mi++)
        #pragma unroll
        for (int ni = 0; ni < NI; ni++)
          acc[mi][ni] = __builtin_amdgcn_mfma_f32_16x16x32_bf16(af[mi][ks], bfr[ni][ks], acc[mi][ni], 0, 0, 0);
    __syncthreads();
  }

  #pragma unroll
  for (int mi = 0; mi < 4; mi++) {
    #pragma unroll
    for (int ni = 0; ni < NI; ni++) {
      const int col = bn + wc * (NI * 16) + ni * 16 + (lane & 15);
      float bv = 0.f;
      if (EPI != EPI_NONE) bv = bias[col];
      #pragma unroll
      for (int r = 0; r < 4; r++) {
        const int row = bm + wr * 64 + mi * 16 + ((lane >> 4) << 2) + r;
        const float vacc = acc[mi][ni][r];
        const size_t idx = (size_t)row * N + col;
        if (EPI == EPI_NONE) {
          ((obf*)Cout)[idx] = __float2bfloat16(vacc);
        } else if (EPI == EPI_BIAS_RES_F32OUT) {
          const float x0 = ((const float*)resid)[idx];
          ((float*)Cout)[idx] = vacc + bv + x0;
        } else if (EPI == EPI_BIAS_GELU) {
          const float u = vacc + bv;
          ((obf*)Cout)[idx] = __float2bfloat16(0.5f * u * (1.f + erff(u * 0.70710678118f)));
        } else {   // EPI_BIAS_RESF32_F32OUT
          const float x0 = ((const float*)resid)[idx];
          ((float*)Cout)[idx] = vacc + bv + x0;
        }
      }
    }
  }
}

// ---------------- V transpose: vt[b][h][d][n] = qkv[b][n][2C + h*64 + d] ----------------
__global__ void __launch_bounds__(256) vtrans_kernel(const obf* __restrict__ qkv, obf* __restrict__ vt)
{
  const int bh = blockIdx.y;             // 0..31  (b*16+h)
  const int b = bh >> 4, h = bh & 15;
  const int n0 = blockIdx.x * 64;        // 32 tiles over N=2048
  __shared__ __bf16 tile[64][72];        // +8 pad
  const int t = threadIdx.x;
  {
    const int n = t >> 2;
    const int c0 = (t & 3) * 16;
    const __bf16* src = (const __bf16*)qkv + ((size_t)(b * 2048 + n0 + n)) * 3072 + 2048 + h * 64 + c0;
    bf16x8 u0 = *(const bf16x8*)src;
    bf16x8 u1 = *(const bf16x8*)(src + 8);
    #pragma unroll
    for (int j = 0; j < 8; j++) { tile[n][c0 + j] = u0[j]; tile[n][c0 + 8 + j] = u1[j]; }
  }
  __syncthreads();
  {
    const int d = t >> 2;
    const int c0 = (t & 3) * 16;
    bf16x8 o0, o1;
    #pragma unroll
    for (int j = 0; j < 8; j++) { o0[j] = tile[c0 + j][d]; o1[j] = tile[c0 + 8 + j][d]; }
    __bf16* dst = (__bf16*)vt + ((size_t)bh * 64 + d) * 2048 + n0 + c0;
    *(bf16x8*)dst = o0;
    *(bf16x8*)(dst + 8) = o1;
  }
}

// ---------------- Flash attention fwd ----------------
// Round-16 structure kept: KV=64, 8 waves / 512 threads, Q-tile 128, no-max
// softmax, XCD swizzle, double-buffered Ks/Vs with ONE barrier per tile.
__global__ void __launch_bounds__(512, 2) attn_kernel(
    const obf* __restrict__ qkv_, const obf* __restrict__ vt_, obf* __restrict__ ao)
{
  const __bf16* qkv = (const __bf16*)qkv_;
  const __bf16* vt  = (const __bf16*)vt_;
  const int bid = blockIdx.x;            // 0..511
  const int xcd = bid & 7, idx = bid >> 3;
  const int bh = xcd * 4 + (idx >> 4);   // 4 bh per XCD (K/V L2-resident)
  const int q0 = (idx & 15) * 128;
  const int b = bh >> 4, h = bh & 15;
  const int tid = threadIdx.x, lane = tid & 63, w = tid >> 6;   // w 0..7
  const int l15 = lane & 15, hi = lane >> 4;

  __shared__ __align__(16) char Ks[2][64 * 128];   // [kv=64][d=64]*2B, swizzled
  __shared__ __align__(16) char Vs[2][64 * 128];   // [d=64][kv=64]*2B, swizzled
  __shared__ __align__(16) char Ps[8 * 16 * 128];  // per-wave [16 q][64 kv]*2B, swz

  bf16x8 qf[2];
  {
    const int qrow = q0 + w * 16 + l15;
    #pragma unroll
    for (int ks = 0; ks < 2; ks++)
      qf[ks] = *(const bf16x8*)(qkv + ((size_t)(b * 2048 + qrow)) * 3072 + h * 64 + ks * 32 + hi * 8);
  }

  f32x4 o[4];
  #pragma unroll
  for (int j = 0; j < 4; j++) { o[j][0]=0.f; o[j][1]=0.f; o[j][2]=0.f; o[j][3]=0.f; }
  float lrow[4] = { 0.f, 0.f, 0.f, 0.f };

  const float kfac = 0.125f * 1.44269504089f;  // scale * log2(e)

  const int kr = tid >> 3, kc = (tid & 7) * 8;   // staging coords (1 chunk/thread)
  const int kcb = (tid & 7) * 16;
  const int kswz = kcb ^ ((kr & 7) << 4);

  // ---- prologue: stage tile 0 into buf 0 ----
  bf16x8 pk, pv;
  pk = *(const bf16x8*)(qkv + ((size_t)(b * 2048 + kr)) * 3072 + 1024 + h * 64 + kc);
  pv = *(const bf16x8*)(vt + ((size_t)bh * 64 + kr) * 2048 + kc);
  *(bf16x8*)(Ks[0] + kr * 128 + kswz) = pk;
  *(bf16x8*)(Vs[0] + kr * 128 + kswz) = pv;
  __syncthreads();

  for (int kt = 0; kt < 2048; kt += 64) {
    const int cur = (kt >> 6) & 1;
    if (kt + 64 < 2048) {
      pk = *(const bf16x8*)(qkv + ((size_t)(b * 2048 + kt + 64 + kr)) * 3072 + 1024 + h * 64 + kc);
      pv = *(const bf16x8*)(vt + ((size_t)bh * 64 + kr) * 2048 + kt + 64 + kc);
    }

    f32x4 s[4];
    #pragma unroll
    for (int j = 0; j < 4; j++) { s[j][0]=0.f; s[j][1]=0.f; s[j][2]=0.f; s[j][3]=0.f; }
    #pragma unroll
    for (int ni = 0; ni < 4; ni++) {
      const int r = ni * 16 + l15;
      const bf16x8 kf0 = *(const bf16x8*)(Ks[cur] + r * 128 + ((hi * 16) ^ ((r & 7) << 4)));
      const bf16x8 kf1 = *(const bf16x8*)(Ks[cur] + r * 128 + ((64 + hi * 16) ^ ((r & 7) << 4)));
      s[ni] = __builtin_amdgcn_mfma_f32_16x16x32_bf16(qf[0], kf0, s[ni], 0, 0, 0);
      s[ni] = __builtin_amdgcn_mfma_f32_16x16x32_bf16(qf[1], kf1, s[ni], 0, 0, 0);
    }

    #pragma unroll
    for (int r = 0; r < 4; r++) {
      const int qrl = (hi << 2) + r;
      char* psrow = Ps + w * 2048 + qrl * 128;
      float psum = 0.f;
      #pragma unroll
      for (int ni = 0; ni < 4; ni++) {
        const float p = exp2f(s[ni][r] * kfac);
        psum += p;
        *(__bf16*)(psrow + (((ni * 16 + l15) * 2) ^ ((qrl & 7) << 4))) = (__bf16)p;
      }
      lrow[r] += psum;
    }

    #pragma unroll
    for (int ks = 0; ks < 2; ks++) {
      const int rr = l15;
      const bf16x8 pa = *(const bf16x8*)(Ps + w * 2048 + rr * 128 + (((ks * 32 + hi * 8) * 2) ^ ((rr & 7) << 4)));
      #pragma unroll
      for (int df = 0; df < 4; df++) {
        const int dr = df * 16 + l15;
        const int cb = (ks * 32 + hi * 8) * 2;
        const bf16x8 vb = *(const bf16x8*)(Vs[cur] + dr * 128 + (cb ^ ((dr & 7) << 4)));
        o[df] = __builtin_amdgcn_mfma_f32_16x16x32_bf16(pa, vb, o[df], 0, 0, 0);
      }
    }

    if (kt + 64 < 2048) {
      *(bf16x8*)(Ks[cur ^ 1] + kr * 128 + kswz) = pk;
      *(bf16x8*)(Vs[cur ^ 1] + kr * 128 + kswz) = pv;
    }
    __syncthreads();
  }

  #pragma unroll
  for (int r = 0; r < 4; r++) {
    lrow[r] += __shfl_xor(lrow[r], 1);
    lrow[r] += __shfl_xor(lrow[r], 2);
    lrow[r] += __shfl_xor(lrow[r], 4);
    lrow[r] += __shfl_xor(lrow[r], 8);
  }
  #pragma unroll
  for (int r = 0; r < 4; r++) {
    const float inv = 1.f / lrow[r];
    const int qrow = q0 + w * 16 + (hi << 2) + r;
    #pragma unroll
    for (int df = 0; df < 4; df++) {
      const int col = h * 64 + df * 16 + l15;
      ao[((size_t)(b * 2048 + qrow)) * 1024 + col] = __float2bfloat16(o[df][r] * inv);
    }
  }
}

// ---------------- launch ----------------
// ws layout (64 MB total, slots time-multiplexed):
//   [ 0,16M)  x2   f32 [4096][1024]
//   [16,24M)  h    bf16 [4096][1024]          -> later wb_w2 (8MB) after h dies
//   [24,48M)  qkv  bf16 [4096][3072]          -> later part of m1
//   [48,56M)  ao   bf16 [4096][1024]          -> later part of m1 (m1 spans 24..56M)
//   [56,64M)  SLOT: wb_qkv(6M) -> vt(8M) -> wb_proj(2M) -> wb_w1(8M)
extern "C" void kernel_launch(void* const* d_in, const int* in_sizes, int n_in,
                              void* d_out, int out_size, void* d_ws, size_t ws_size,
                              hipStream_t stream) {
  const float* x      = (const float*)d_in[0];
  const float* ln1_g  = (const float*)d_in[1];
  const float* ln1_b  = (const float*)d_in[2];
  const float* qkv_w  = (const float*)d_in[3];
  const float* proj_w = (const float*)d_in[4];
  const float* proj_b = (const float*)d_in[5];
  const float* ln2_g  = (const float*)d_in[6];
  const float* ln2_b  = (const float*)d_in[7];
  const float* w1     = (const float*)d_in[8];
  const float* b1     = (const float*)d_in[9];
  const float* w2     = (const float*)d_in[10];
  const float* b2     = (const float*)d_in[11];
  float* out = (float*)d_out;                       // reference output dtype: float32

  char* ws = (char*)d_ws;
  float* x2   = (float*)ws;                        // 16 MB
  obf*   h    = (obf*)(ws + (16u << 20));          //  8 MB
  obf*   qkv  = (obf*)(ws + (24u << 20));          // 24 MB
  obf*   ao   = (obf*)(ws + (48u << 20));          //  8 MB
  obf*   m1   = (obf*)(ws + (24u << 20));          // 32 MB (overlays qkv+ao, both dead)
  __bf16* slot = (__bf16*)(ws + (56u << 20));      //  8 MB multi-use
  __bf16* wb_w2 = (__bf16*)(ws + (16u << 20));     //  8 MB (overlays h after it dies)

  const int M = 4096;

  // 0. wb_qkv = bf16(qkv_w)
  f2b_kernel<<<(3072 * 1024 / 8 + 255) / 256, 256, 0, stream>>>(qkv_w, slot, 3072 * 1024 / 8);
  // 1. LN1: x -> h
  ln_kernel<<<M, 256, 0, stream>>>(x, ln1_g, ln1_b, h);
  // 2. qkv = h @ qkv_w^T
  gemm_bt<EPI_NONE, 4><<<dim3(3072 / 128, M / 128), 256, 0, stream>>>(
      h, (const obf*)slot, qkv, nullptr, nullptr, M, 3072, 1024);
  // 3. vt = transpose(V)   (overwrites wb_qkv, now dead)
  vtrans_kernel<<<dim3(32, 32), 256, 0, stream>>>(qkv, (obf*)slot);
  // 4. attention -> ao   (512 blocks x 512 threads, KV=64 dbuf 1-barrier)
  attn_kernel<<<512, 512, 0, stream>>>(qkv, (const obf*)slot, ao);
  // 5. wb_proj = bf16(proj_w)   (overwrites vt, now dead)
  f2b_kernel<<<(1024 * 1024 / 8 + 255) / 256, 256, 0, stream>>>(proj_w, slot, 1024 * 1024 / 8);
  // 6. x2 = x + ao @ proj_w^T + proj_b   (f32 out; BN=64 -> 512 blocks)
  gemm_bt<EPI_BIAS_RES_F32OUT, 2><<<dim3(1024 / 64, M / 128), 256, 0, stream>>>(
      ao, (const obf*)slot, x2, proj_b, x, M, 1024, 1024);
  // 7. LN2: x2 -> h
  ln_kernel<<<M, 256, 0, stream>>>(x2, ln2_g, ln2_b, h);
  // 8. wb_w1 = bf16(w1)   (overwrites wb_proj, now dead)
  f2b_kernel<<<(4096 * 1024 / 8 + 255) / 256, 256, 0, stream>>>(w1, slot, 4096 * 1024 / 8);
  // 9. m1 = gelu(h @ w1^T + b1)
  gemm_bt<EPI_BIAS_GELU, 4><<<dim3(4096 / 128, M / 128), 256, 0, stream>>>(
      h, (const obf*)slot, m1, b1, nullptr, M, 4096, 1024);
  // 10. wb_w2 = bf16(w2)   (overwrites h, now dead)
  f2b_kernel<<<(4096 * 1024 / 8 + 255) / 256, 256, 0, stream>>>(w2, wb_w2, 4096 * 1024 / 8);
  // 11. out = x2 + m1 @ w2^T + b2   (f32 out -> d_out; BN=64 -> 512 blocks)
  gemm_bt<EPI_BIAS_RESF32_F32OUT, 2><<<dim3(1024 / 64, M / 128), 256, 0, stream>>>(
      m1, (const obf*)wb_w2, out, b2, x2, M, 1024, 4096);
}